// Round 12
// baseline (188.194 us; speedup 1.0000x reference)
//
#include <hip/hip_runtime.h>
#include <cstdint>

// MXFP4 fake-quant linear: out = qdq(A) @ qdq(W)^T + bias
// Stage 1: quantize fp32 -> packed e2m1 + e8m0 scales. Scale layout:
//          groups of 8 k-blocks interleaved per row: sc[(kb/8)][row][kb%8]
//          -> GEMM fetches all 8 scale bytes of a row in one 8B load.
// Stage 2: fp4 GEMM, 256x256 tile, BK=256 (4 k-steps of 32x32x64), 512 thr
//          = 8 waves (2M x 4N), double-buffered 128 KB LDS, 1 WG/CU,
//          grid 256 (XCD-bijective), v8's counted-vmcnt skeleton, scale
//          groups prefetched 1 iter ahead (macro unroll-2, static indices).
// Rationale: r3/r5/v8 all ~37-40us with identical 268 MB staged volume
// across different sync structures => time tracks staged bytes. 256^2
// halves staged bytes (134 MB) and adds 4x/2x LDS read reuse.
// (Resubmission: round-11 bench failed on GPU acquisition timeout.)

#define BM 256
#define BN 256
#define BK 256      // K elements per sync iteration = 4 k-steps of 64

typedef float floatx16 __attribute__((ext_vector_type(16)));
typedef int intx8 __attribute__((ext_vector_type(8)));

#define GLOBAL_AS __attribute__((address_space(1)))
#define LDS_AS __attribute__((address_space(3)))

// ---------------- quantize fp32 -> packed fp4 + e8m0 scales ----------------

__device__ __forceinline__ int enc1(float x, float inv) {
    float q = x * inv;                         // inv = 2^-(e-2), exact
    q = fminf(fmaxf(q, -6.0f), 6.0f);
    int s = (int)(__float_as_uint(q) >> 31) << 3;
    float aq = fabsf(q);
    float ilsb = aq < 2.0f ? 2.0f : (aq < 4.0f ? 1.0f : 0.5f);
    float lsb  = aq < 2.0f ? 0.5f : (aq < 4.0f ? 1.0f : 2.0f);
    float ar = rintf(aq * ilsb) * lsb;         // RNE onto e2m1 grid
    int c;
    if (ar < 2.0f)      c = (int)(ar * 2.0f);  // 0,.5,1,1.5 -> 0..3
    else if (ar < 4.0f) c = 2 + (int)ar;       // 2,3 -> 4,5
    else                c = 4 + (int)(ar * 0.5f); // 4,6 -> 6,7
    return c | s;
}

__global__ void quant_mxfp4_v5(const float* __restrict__ A, uint8_t* __restrict__ Aq,
                               uint8_t* __restrict__ Asc,
                               const float* __restrict__ W, uint8_t* __restrict__ Wq,
                               uint8_t* __restrict__ Wsc,
                               long na4, long ntot4, int s4, long Mr, long Nr) {
    long t = (long)blockIdx.x * 256 + threadIdx.x;
    if (t >= ntot4) return;
    const float* src; uint8_t* dq; uint8_t* ds; long idx; long rows;
    if (t < na4) { src = A; dq = Aq; ds = Asc; idx = t; rows = Mr; }
    else         { src = W; dq = Wq; ds = Wsc; idx = t - na4; rows = Nr; }

    float4 f = ((const float4*)src)[idx];
    float amax = fmaxf(fmaxf(fabsf(f.x), fabsf(f.y)),
                       fmaxf(fabsf(f.z), fabsf(f.w)));
    amax = fmaxf(amax, __shfl_xor(amax, 1));
    amax = fmaxf(amax, __shfl_xor(amax, 2));
    amax = fmaxf(amax, __shfl_xor(amax, 4));

    int ebits = (int)((__float_as_uint(amax) >> 23) & 0xff);
    int sb;
    float inv;
    if (amax > 0.0f) {
        sb = ebits - 2; if (sb < 0) sb = 0;
        inv = __uint_as_float((unsigned)((256 - ebits) & 255) << 23);
    } else {
        sb = 127;              // scale 1.0, all-zero block
        inv = 0.0f;
    }

    int c0 = enc1(f.x, inv), c1 = enc1(f.y, inv);
    int c2 = enc1(f.z, inv), c3 = enc1(f.w, inv);
    ((unsigned short*)dq)[idx] =
        (unsigned short)(c0 | (c1 << 4) | (c2 << 8) | (c3 << 12));
    if ((idx & 7) == 0) {
        long m  = idx >> s4;                             // row
        int  kb = (int)((idx & ((1L << s4) - 1)) >> 3);  // k-block (32 elems)
        // interleaved-8 layout: [kb/8][row][kb%8]
        ds[((size_t)(kb >> 3) * rows + m) * 8 + (kb & 7)] = (uint8_t)sb;
    }
}

// ---------- fp4 GEMM: C[M,N] = (Aq,Asc) x (Wq,Wsc)^T + bias ----------
// 512 threads = 8 waves 2(M) x 4(N); per-wave output 128x64 = acc[4][2]
// of 32x32 blocks (16 f32 each).
// 32x32x64 frag: A row = lane&31, k-half (16B = 32 elems) = lane>>5.
// C/D: col = lane&31 (n), row = (reg&3) + 8*(reg>>2) + 4*(lane>>5) (m).
// LDS rows 128B = 8 x 16B chunks; slot c holds global chunk c^(row&7)
// (DMA source AND read side). All verified rounds 5-10.
//
// Per iteration (buf p = t&1):
//   prefetch scale groups (t+1): 6 x 8B loads  [vmem]
//   per-ks pipelined: 6 ds_read_b128 (ks+1) || 8 MFMA (ks)
//   lgkmcnt(0); BAR1 (all waves done reading buf p)
//   stage(t+2) into buf p: 8 x 16B DMA
//   vmcnt(8): drains stage(t+1)+scales(t+1), leaves stage(t+2); BAR2
// No full vmcnt drain in the main loop.

#define GITER(T, CUR, NXT)                                                     \
  {                                                                            \
    const int p_ = (T) & 1;                                                    \
    const uint8_t* pa_ = sA[p_];                                               \
    const uint8_t* pb_ = sB[p_];                                               \
    if ((T) + 1 < NT) {                                                        \
      _Pragma("unroll") for (int mi = 0; mi < 4; ++mi)                         \
        sgA[NXT][mi] = *(const uint2*)(Asc +                                   \
            ((size_t)((T) + 1) * M + m0 + rA0 + mi * 32) * 8);                 \
      _Pragma("unroll") for (int ni = 0; ni < 2; ++ni)                         \
        sgB[NXT][ni] = *(const uint2*)(Wsc +                                   \
            ((size_t)((T) + 1) * N + n0 + rB0 + ni * 32) * 8);                 \
    }                                                                          \
    __builtin_amdgcn_sched_barrier(0);                                         \
    int4 fa_[4], fb_[2];                                                       \
    _Pragma("unroll") for (int mi = 0; mi < 4; ++mi)                           \
      fa_[mi] = *(const int4*)(pa_ + (rA0 + mi * 32) * 128 + (q2 ^ swz) * 16); \
    _Pragma("unroll") for (int ni = 0; ni < 2; ++ni)                           \
      fb_[ni] = *(const int4*)(pb_ + (rB0 + ni * 32) * 128 + (q2 ^ swz) * 16); \
    __builtin_amdgcn_s_setprio(1);                                             \
    _Pragma("unroll") for (int ks = 0; ks < 4; ++ks) {                         \
      int4 na_[4], nb_[2];                                                     \
      if (ks < 3) {                                                            \
        const int off_ = (((ks + 1) * 2 + q2) ^ swz) * 16;                     \
        _Pragma("unroll") for (int mi = 0; mi < 4; ++mi)                       \
          na_[mi] = *(const int4*)(pa_ + (rA0 + mi * 32) * 128 + off_);        \
        _Pragma("unroll") for (int ni = 0; ni < 2; ++ni)                       \
          nb_[ni] = *(const int4*)(pb_ + (rB0 + ni * 32) * 128 + off_);        \
      }                                                                        \
      int sav_[4], sbv_[2];                                                    \
      _Pragma("unroll") for (int mi = 0; mi < 4; ++mi)                         \
        sav_[mi] = (int)(((ks < 2) ? (sgA[CUR][mi].x >> ((ks * 2 + q2) * 8))   \
                   : (sgA[CUR][mi].y >> (((ks - 2) * 2 + q2) * 8))) & 0xffu);  \
      _Pragma("unroll") for (int ni = 0; ni < 2; ++ni)                         \
        sbv_[ni] = (int)(((ks < 2) ? (sgB[CUR][ni].x >> ((ks * 2 + q2) * 8))   \
                   : (sgB[CUR][ni].y >> (((ks - 2) * 2 + q2) * 8))) & 0xffu);  \
      intx8 b80_, b81_;                                                        \
      b80_[0] = fb_[0].x; b80_[1] = fb_[0].y; b80_[2] = fb_[0].z;              \
      b80_[3] = fb_[0].w; b80_[4] = 0; b80_[5] = 0; b80_[6] = 0; b80_[7] = 0;  \
      b81_[0] = fb_[1].x; b81_[1] = fb_[1].y; b81_[2] = fb_[1].z;              \
      b81_[3] = fb_[1].w; b81_[4] = 0; b81_[5] = 0; b81_[6] = 0; b81_[7] = 0;  \
      _Pragma("unroll") for (int mi = 0; mi < 4; ++mi) {                       \
        intx8 a8_;                                                             \
        a8_[0] = fa_[mi].x; a8_[1] = fa_[mi].y; a8_[2] = fa_[mi].z;            \
        a8_[3] = fa_[mi].w; a8_[4] = 0; a8_[5] = 0; a8_[6] = 0; a8_[7] = 0;    \
        acc[mi][0] = __builtin_amdgcn_mfma_scale_f32_32x32x64_f8f6f4(          \
            a8_, b80_, acc[mi][0], 4, 4, 0, sav_[mi], 0, sbv_[0]);             \
        acc[mi][1] = __builtin_amdgcn_mfma_scale_f32_32x32x64_f8f6f4(          \
            a8_, b81_, acc[mi][1], 4, 4, 0, sav_[mi], 0, sbv_[1]);             \
      }                                                                        \
      if (ks < 3) {                                                            \
        _Pragma("unroll") for (int mi = 0; mi < 4; ++mi) fa_[mi] = na_[mi];    \
        _Pragma("unroll") for (int ni = 0; ni < 2; ++ni) fb_[ni] = nb_[ni];    \
      }                                                                        \
    }                                                                          \
    __builtin_amdgcn_s_setprio(0);                                             \
    if ((T) + 1 < NT) {                                                        \
      asm volatile("s_waitcnt lgkmcnt(0)" ::: "memory");                       \
      __builtin_amdgcn_sched_barrier(0);                                       \
      __builtin_amdgcn_s_barrier();                                            \
      if ((T) + 2 < NT) stage((T) + 2);                                        \
      __builtin_amdgcn_sched_barrier(0);                                       \
      if ((T) + 2 < NT) asm volatile("s_waitcnt vmcnt(8)" ::: "memory");       \
      else              asm volatile("s_waitcnt vmcnt(0)" ::: "memory");       \
      __builtin_amdgcn_sched_barrier(0);                                       \
      __builtin_amdgcn_s_barrier();                                            \
    }                                                                          \
  }

__global__ __launch_bounds__(512, 2) void gemm_fp4_v9(
        const uint8_t* __restrict__ Aq, const uint8_t* __restrict__ Asc,
        const uint8_t* __restrict__ Wq, const uint8_t* __restrict__ Wsc,
        const float* __restrict__ bias, float* __restrict__ C,
        int M, int N, int K) {
    __shared__ __align__(16) uint8_t sA[2][BM * 128];  // 2 x 32 KB
    __shared__ __align__(16) uint8_t sB[2][BN * 128];  // 2 x 32 KB

    const int tid = threadIdx.x;
    const int lane = tid & 63;
    const int w = tid >> 6;          // 0..7
    const int wr = w >> 2;           // 0..1 (M): rows wr*128
    const int wc = w & 3;            // 0..3 (N): cols wc*64
    const int row32 = lane & 31;
    const int q2 = lane >> 5;        // k-half within a 64-K step

    // XCD-bijective remap: grid 256 (id%8 = XCD); each XCD owns 4 A-panels
    // (1 MB) x all 8 B-panels (2.1 MB) = 3.1 MB < 4 MB L2.
    const int id = blockIdx.x;
    const int g = id & 7, h = id >> 3;   // h 0..31
    const int by = g * 4 + (h & 3);      // 0..31
    const int bx = h >> 2;               // 0..7
    const int m0 = by * BM;
    const int n0 = bx * BN;
    const int KB2 = K >> 1;
    const int NT = K / BK;               // 8 (even)

    const int rA0 = wr * 128 + row32;    // A row within tile
    const int rB0 = wc * 64 + row32;     // B row within tile
    const int swz = row32 & 7;

    floatx16 acc[4][2];
#pragma unroll
    for (int i = 0; i < 4; i++)
#pragma unroll
        for (int j = 0; j < 2; j++)
#pragma unroll
            for (int r = 0; r < 16; r++) acc[i][j][r] = 0.f;

    // 8 uniform DMA insts/thread/iter: 4 A + 4 B (16B each), 64 KB total
    auto stage = [&](int tt) {
        const int bb = tt & 1;
        const int kb = tt * 128;             // bytes along packed K
#pragma unroll
        for (int it = 0; it < 4; ++it) {
            int idx = it * 512 + tid;        // 0..2047 16B chunks
            int row = idx >> 3, c = idx & 7;
            int gc = c ^ (row & 7);          // pre-swizzled source chunk
            const uint8_t* src = Aq + (size_t)(m0 + row) * KB2 + kb + gc * 16;
            __builtin_amdgcn_global_load_lds((GLOBAL_AS void*)src,
                (LDS_AS void*)(&sA[bb][idx * 16]), 16, 0, 0);
        }
#pragma unroll
        for (int it = 0; it < 4; ++it) {
            int idx = it * 512 + tid;
            int row = idx >> 3, c = idx & 7;
            int gc = c ^ (row & 7);
            const uint8_t* src = Wq + (size_t)(n0 + row) * KB2 + kb + gc * 16;
            __builtin_amdgcn_global_load_lds((GLOBAL_AS void*)src,
                (LDS_AS void*)(&sB[bb][idx * 16]), 16, 0, 0);
        }
    };

    uint2 sgA[2][4], sgB[2][2];          // scale groups, static-indexed only

    // ---- prologue: stage(0), scales(0), stage(1); drain all but stage(1) ----
    stage(0);
    __builtin_amdgcn_sched_barrier(0);
#pragma unroll
    for (int mi = 0; mi < 4; ++mi)
        sgA[0][mi] = *(const uint2*)(Asc + ((size_t)0 * M + m0 + rA0 + mi * 32) * 8);
#pragma unroll
    for (int ni = 0; ni < 2; ++ni)
        sgB[0][ni] = *(const uint2*)(Wsc + ((size_t)0 * N + n0 + rB0 + ni * 32) * 8);
    __builtin_amdgcn_sched_barrier(0);
    stage(1);
    __builtin_amdgcn_sched_barrier(0);
    asm volatile("s_waitcnt vmcnt(8)" ::: "memory");
    __builtin_amdgcn_sched_barrier(0);
    __builtin_amdgcn_s_barrier();

    for (int t = 0; t < NT; t += 2) {
        GITER(t, 0, 1);
        GITER(t + 1, 1, 0);
    }

    // ---- epilogue: col = lane&31 (n), row = (r&3)+8*(r>>2)+4*q2 (m) ----
#pragma unroll
    for (int ni = 0; ni < 2; ++ni) {
        int n = n0 + wc * 64 + ni * 32 + row32;
        float bv = bias[n];
#pragma unroll
        for (int mi = 0; mi < 4; ++mi) {
            int mb = m0 + wr * 128 + mi * 32 + 4 * q2;
#pragma unroll
            for (int r = 0; r < 16; ++r) {
                int m = mb + (r & 3) + 8 * (r >> 2);
                C[(size_t)m * N + n] = acc[mi][ni][r] + bv;
            }
        }
    }
}

// ---------------- launch ----------------

extern "C" void kernel_launch(void* const* d_in, const int* in_sizes, int n_in,
                              void* d_out, int out_size, void* d_ws, size_t ws_size,
                              hipStream_t stream) {
    const float* inp  = (const float*)d_in[0];
    const float* wgt  = (const float*)d_in[1];
    const float* bias = (const float*)d_in[2];
    float* out = (float*)d_out;

    const int N = in_sizes[2];                 // 2048
    const int K = in_sizes[1] / N;             // 2048
    const long M = (long)in_sizes[0] / K;      // 8192

    uint8_t* Aq4 = (uint8_t*)d_ws;             // M*K/2
    uint8_t* Wq4 = Aq4 + (size_t)M * K / 2;    // N*K/2
    uint8_t* Asc = Wq4 + (size_t)N * K / 2;    // M*K/32, layout [K/256][M][8]
    uint8_t* Wsc = Asc + (size_t)M * K / 32;   // N*K/32, layout [K/256][N][8]

    int s4 = 0;
    while ((1 << s4) < (K >> 2)) ++s4;         // log2(K/4) = 9

    long na4   = (long)M * K / 4;
    long ntot4 = na4 + (long)N * K / 4;
    quant_mxfp4_v5<<<dim3((ntot4 + 255) / 256), dim3(256), 0, stream>>>(
        inp, Aq4, Asc, wgt, Wq4, Wsc, na4, ntot4, s4, M, (long)N);

    dim3 grid((N / BN) * (int)(M / BM));       // 8*32 = 256 WGs = 1/CU
    gemm_fp4_v9<<<grid, dim3(512), 0, stream>>>(
        Aq4, Asc, Wq4, Wsc, bias, out, (int)M, N, K);
}